// Round 1
// baseline (485.709 us; speedup 1.0000x reference)
//
#include <hip/hip_runtime.h>

typedef __bf16 bf16x8 __attribute__((ext_vector_type(8)));
typedef unsigned short u16x8 __attribute__((ext_vector_type(8)));
typedef float f32x4 __attribute__((ext_vector_type(4)));

#define B_    8
#define N_    1024
#define DIM_  1024
#define H_    8
#define HD_   128
#define SCALE_ 0.08838834764831845f

__device__ __forceinline__ unsigned short f2bf(float x) {
  unsigned int u = __float_as_uint(x);
  u += 0x7fffu + ((u >> 16) & 1u);           // RNE
  return (unsigned short)(u >> 16);
}
__device__ __forceinline__ float bf2f(unsigned short h) {
  return __uint_as_float(((unsigned int)h) << 16);
}
__device__ __forceinline__ f32x4 mfma16(u16x8 a, u16x8 b, f32x4 c) {
  return __builtin_amdgcn_mfma_f32_16x16x32_bf16(
      __builtin_bit_cast(bf16x8, a), __builtin_bit_cast(bf16x8, b), c, 0, 0, 0);
}
// split x into bf16 hi/lo pairs for 4 values and store packed u32s into LDS row
// layout: rowbase + hl_off*hl + k*2, XOR-swizzled with swz (bits 4..6)
__device__ __forceinline__ void pack_store(char* rowbase, int swz, int hl_off,
                                           int kp, float x0, float x1, float x2, float x3) {
  unsigned short h0 = f2bf(x0), h1 = f2bf(x1), h2 = f2bf(x2), h3 = f2bf(x3);
  unsigned short g0 = f2bf(x0 - bf2f(h0)), g1 = f2bf(x1 - bf2f(h1));
  unsigned short g2 = f2bf(x2 - bf2f(h2)), g3 = f2bf(x3 - bf2f(h3));
  *(unsigned int*)(rowbase + ((kp * 2) ^ swz))              = (unsigned int)h0 | ((unsigned int)h1 << 16);
  *(unsigned int*)(rowbase + ((kp * 2 + 4) ^ swz))          = (unsigned int)h2 | ((unsigned int)h3 << 16);
  *(unsigned int*)(rowbase + ((hl_off + kp * 2) ^ swz))     = (unsigned int)g0 | ((unsigned int)g1 << 16);
  *(unsigned int*)(rowbase + ((hl_off + kp * 2 + 4) ^ swz)) = (unsigned int)g2 | ((unsigned int)g3 << 16);
}

struct K1Smem {
  unsigned short p[64 * 1024];                 // 131072 B: p[row][key] bf16, byte ^ ((row&7)<<4)
  union {
    unsigned short kbuf[2 * 16 * 2 * 128];     // [half][key][hl][d], byte ^ ((key&7)<<4)  (16384 B)
    struct {
      unsigned short vt[2 * 128 * 40];         // [hl][d][key(32)+pad8]  (20480 B)
      float partial[2][64];
      float rinv[64];
    } pv;
  } u;
};

__global__ __launch_bounds__(512, 2)
void attn_kernel(const float* __restrict__ gq, const float* __restrict__ gk,
                 const float* __restrict__ gv, float* __restrict__ gattn,
                 float* __restrict__ gao) {
  __shared__ K1Smem sm;
  const int bid = blockIdx.x;
  const int qt = bid & 15, hh = (bid >> 4) & 7, bb = bid >> 7;
  const int tid = threadIdx.x;
  const int wid = tid >> 6, lane = tid & 63;
  const int rg = wid >> 1, hf = wid & 1;
  const int l15 = lane & 15, l4 = lane >> 4;

  // ---------------- load Q fragments (pre-scaled, split hi/lo) ----------------
  u16x8 qhi[4], qlo[4];
  {
    const int qrow = qt * 64 + rg * 16 + l15;
    const float* qp = gq + ((size_t)bb * N_ + qrow) * DIM_ + hh * HD_;
    #pragma unroll
    for (int t = 0; t < 4; ++t) {
      const int d0 = t * 32 + l4 * 8;
      float4 f0 = *(const float4*)(qp + d0);
      float4 f1 = *(const float4*)(qp + d0 + 4);
      float vals[8] = {f0.x, f0.y, f0.z, f0.w, f1.x, f1.y, f1.z, f1.w};
      #pragma unroll
      for (int j = 0; j < 8; ++j) {
        float x = vals[j] * SCALE_;
        unsigned short hi = f2bf(x);
        qhi[t][j] = hi;
        qlo[t][j] = f2bf(x - bf2f(hi));
      }
    }
  }

  // ---------------- Phase 1: S = Q K^T (bf16x3), p = exp(S) -> LDS ----------------
  float lsum[4] = {0.f, 0.f, 0.f, 0.f};
  char* const kbase = (char*)sm.u.kbuf + hf * 8192;
  const int ht = rg * 64 + lane;               // 0..255 within this half's 4 waves
  #pragma unroll 1
  for (int it = 0; it < 32; ++it) {
    // stage this half's 16 keys x 128 d
    #pragma unroll
    for (int c0 = 0; c0 < 2; ++c0) {
      const int c = ht + 256 * c0;             // 0..511
      const int key = c >> 5;                  // 0..15
      const int dp = (c & 31) * 4;             // 0..124
      const float* kp = gk + ((size_t)bb * N_ + (hf * 512 + it * 16 + key)) * DIM_ + hh * HD_ + dp;
      float4 f = *(const float4*)kp;
      pack_store(kbase + key * 512, (key & 7) << 4, 256, dp, f.x, f.y, f.z, f.w);
    }
    __syncthreads();
    // 16 rows x 16 keys, K=128 in 4 MFMA k-tiles, 3-term split
    f32x4 a0 = {0.f, 0.f, 0.f, 0.f}, a1 = a0, a2 = a0;
    {
      const int swz = (l15 & 7) << 4;
      const char* krow = kbase + l15 * 512;
      #pragma unroll
      for (int t = 0; t < 4; ++t) {
        const int dbyte = (t * 32 + l4 * 8) * 2;
        u16x8 khi = *(const u16x8*)(krow + (dbyte ^ swz));
        u16x8 klo = *(const u16x8*)(krow + ((256 + dbyte) ^ swz));
        a0 = mfma16(qhi[t], khi, a0);
        a1 = mfma16(qhi[t], klo, a1);
        a2 = mfma16(qlo[t], khi, a2);
      }
    }
    const int keyg = hf * 512 + it * 16 + l15;
    #pragma unroll
    for (int r = 0; r < 4; ++r) {
      float s = (a0[r] + a1[r]) + a2[r];
      s = fminf(s, 60.0f);
      float p = __expf(s);
      lsum[r] += p;
      const int row = rg * 16 + l4 * 4 + r;
      *(unsigned short*)((char*)sm.p + ((row * 2048 + keyg * 2) ^ ((row & 7) << 4))) = f2bf(p);
    }
    __syncthreads();
  }

  // ---------------- rowsums, rinv ----------------
  #pragma unroll
  for (int r = 0; r < 4; ++r) {
    float s = lsum[r];
    s += __shfl_xor(s, 1);
    s += __shfl_xor(s, 2);
    s += __shfl_xor(s, 4);
    s += __shfl_xor(s, 8);
    lsum[r] = s;                                // full sum over this half's keys
  }
  if (l15 == 0) {
    #pragma unroll
    for (int r = 0; r < 4; ++r)
      sm.u.pv.partial[hf][rg * 16 + l4 * 4 + r] = lsum[r];
  }

  auto stageV = [&](int kt) {
    #pragma unroll
    for (int c0 = 0; c0 < 2; ++c0) {
      const int c = tid + 512 * c0;            // 0..1023
      const int key = c & 31;
      const int dp = ((c >> 5) & 31) * 4;
      const float* vp = gv + ((size_t)bb * N_ + kt * 32 + key) * DIM_ + hh * HD_ + dp;
      float4 f = *(const float4*)vp;
      float xs[4] = {f.x, f.y, f.z, f.w};
      #pragma unroll
      for (int j = 0; j < 4; ++j) {
        unsigned short hi = f2bf(xs[j]);
        sm.u.pv.vt[(dp + j) * 40 + key] = hi;
        sm.u.pv.vt[5120 + (dp + j) * 40 + key] = f2bf(xs[j] - bf2f(hi));
      }
    }
  };
  stageV(0);
  __syncthreads();

  float rv4[4];
  #pragma unroll
  for (int r = 0; r < 4; ++r) {
    const int row = rg * 16 + l4 * 4 + r;
    rv4[r] = 1.0f / (lsum[r] + sm.u.pv.partial[1 - hf][row]);
  }
  if (hf == 0 && l15 == 0) {
    #pragma unroll
    for (int r = 0; r < 4; ++r)
      sm.u.pv.rinv[rg * 16 + l4 * 4 + r] = rv4[r];
  }
  __syncthreads();

  // ---------------- write attn = p * rinv ----------------
  {
    float* ab = gattn + (((size_t)(bb * 8 + hh)) * N_ + qt * 64) * N_;
    #pragma unroll 1
    for (int c0 = 0; c0 < 16; ++c0) {
      const int c = tid + 512 * c0;            // 0..8191
      const int row = c >> 7;
      const int cc = c & 127;
      u16x8 pw = *(const u16x8*)((char*)sm.p + ((row * 2048 + cc * 16) ^ ((row & 7) << 4)));
      const float rv = sm.u.pv.rinv[row];
      float4 o0, o1;
      o0.x = bf2f(pw[0]) * rv; o0.y = bf2f(pw[1]) * rv;
      o0.z = bf2f(pw[2]) * rv; o0.w = bf2f(pw[3]) * rv;
      o1.x = bf2f(pw[4]) * rv; o1.y = bf2f(pw[5]) * rv;
      o1.z = bf2f(pw[6]) * rv; o1.w = bf2f(pw[7]) * rv;
      float* dst = ab + (size_t)row * N_ + cc * 8;
      *(float4*)dst = o0;
      *(float4*)(dst + 4) = o1;
    }
  }

  // ---------------- Phase 2: PV (p bf16 x (v_hi + v_lo)) ----------------
  f32x4 oacc[4];
  #pragma unroll
  for (int ct = 0; ct < 4; ++ct) oacc[ct] = f32x4{0.f, 0.f, 0.f, 0.f};
  const int prow = rg * 16 + l15;
  const int pswz = (prow & 7) << 4;
  #pragma unroll 1
  for (int kt = 0; kt < 32; ++kt) {
    u16x8 pa = *(const u16x8*)((char*)sm.p + ((prow * 2048 + kt * 64 + l4 * 16) ^ pswz));
    #pragma unroll
    for (int ct = 0; ct < 4; ++ct) {
      const int d = hf * 64 + ct * 16 + l15;
      const unsigned short* vr = sm.u.pv.vt + d * 40 + l4 * 8;
      u16x8 vh = *(const u16x8*)vr;
      u16x8 vl = *(const u16x8*)(vr + 5120);
      oacc[ct] = mfma16(pa, vh, oacc[ct]);
      oacc[ct] = mfma16(pa, vl, oacc[ct]);
    }
    if (kt < 31) {
      __syncthreads();
      stageV(kt + 1);
      __syncthreads();
    }
  }

  // epilogue: normalized attention output -> workspace (pre-projection)
  {
    const int aorow0 = qt * 64 + rg * 16 + l4 * 4;
    #pragma unroll
    for (int ct = 0; ct < 4; ++ct) {
      const int d = hf * 64 + ct * 16 + l15;
      float* dst = gao + ((size_t)bb * N_ + aorow0) * DIM_ + hh * HD_ + d;
      #pragma unroll
      for (int r = 0; r < 4; ++r)
        dst[(size_t)r * DIM_] = oacc[ct][r] * rv4[r];
    }
  }
}

// ---------------- K2: out = ao @ W^T + b  (bf16x3, 128x128 tiles) ----------------
struct K2Smem {
  unsigned short A[128 * 2 * 32];   // [row][hl][k], byte = row*128 + hl*64 + k*2, ^((row&7)<<4)
  unsigned short Bm[128 * 2 * 32];
};

__global__ __launch_bounds__(512)
void proj_kernel(const float* __restrict__ gao, const float* __restrict__ gw,
                 const float* __restrict__ gbias, float* __restrict__ gout) {
  __shared__ K2Smem sm;
  const int bid = blockIdx.x;
  const int mt = bid >> 3, nt = bid & 7;
  const int m0 = mt * 128, n0 = nt * 128;
  const int tid = threadIdx.x;
  const int wid = tid >> 6, lane = tid & 63;
  const int wr = wid >> 1, wc = wid & 1;       // wave tile: rows wr*32..+32, cols wc*64..+64
  const int l15 = lane & 15, l4 = lane >> 4;

  f32x4 acc[2][4];
  #pragma unroll
  for (int i = 0; i < 2; ++i)
    #pragma unroll
    for (int j = 0; j < 4; ++j) acc[i][j] = f32x4{0.f, 0.f, 0.f, 0.f};

  #pragma unroll 1
  for (int step = 0; step < 32; ++step) {
    const int k0 = step * 32;
    if (step) __syncthreads();
    #pragma unroll
    for (int c0 = 0; c0 < 2; ++c0) {
      const int c = tid + 512 * c0;            // 0..1023
      const int row = c >> 3;                  // 0..127
      const int kp = (c & 7) * 4;
      float4 fa = *(const float4*)(gao + (size_t)(m0 + row) * DIM_ + k0 + kp);
      float4 fb = *(const float4*)(gw + (size_t)(n0 + row) * DIM_ + k0 + kp);
      const int swz = (row & 7) << 4;
      pack_store((char*)sm.A + row * 128, swz, 64, kp, fa.x, fa.y, fa.z, fa.w);
      pack_store((char*)sm.Bm + row * 128, swz, 64, kp, fb.x, fb.y, fb.z, fb.w);
    }
    __syncthreads();

    u16x8 ah[2], al[2], bh[4], bl[4];
    #pragma unroll
    for (int t = 0; t < 2; ++t) {
      const int row = wr * 32 + t * 16 + l15;
      const char* rp = (char*)sm.A + row * 128;
      const int swz = (row & 7) << 4;
      ah[t] = *(const u16x8*)(rp + ((l4 * 16) ^ swz));
      al[t] = *(const u16x8*)(rp + ((64 + l4 * 16) ^ swz));
    }
    #pragma unroll
    for (int t = 0; t < 4; ++t) {
      const int col = wc * 64 + t * 16 + l15;
      const char* rp = (char*)sm.Bm + col * 128;
      const int swz = (col & 7) << 4;
      bh[t] = *(const u16x8*)(rp + ((l4 * 16) ^ swz));
      bl[t] = *(const u16x8*)(rp + ((64 + l4 * 16) ^ swz));
    }
    #pragma unroll
    for (int i = 0; i < 2; ++i)
      #pragma unroll
      for (int j = 0; j < 4; ++j)
        acc[i][j] = mfma16(ah[i], bh[j], acc[i][j]);
    #pragma unroll
    for (int i = 0; i < 2; ++i)
      #pragma unroll
      for (int j = 0; j < 4; ++j)
        acc[i][j] = mfma16(ah[i], bl[j], acc[i][j]);
    #pragma unroll
    for (int i = 0; i < 2; ++i)
      #pragma unroll
      for (int j = 0; j < 4; ++j)
        acc[i][j] = mfma16(al[i], bh[j], acc[i][j]);
  }

  #pragma unroll
  for (int i = 0; i < 2; ++i) {
    #pragma unroll
    for (int j = 0; j < 4; ++j) {
      const int col = n0 + wc * 64 + j * 16 + l15;
      const float bv = gbias[col];
      float* dst = gout + (size_t)(m0 + wr * 32 + i * 16 + l4 * 4) * DIM_ + col;
      #pragma unroll
      for (int r = 0; r < 4; ++r)
        dst[(size_t)r * DIM_] = acc[i][j][r] + bv;
    }
  }
}

extern "C" void kernel_launch(void* const* d_in, const int* in_sizes, int n_in,
                              void* d_out, int out_size, void* d_ws, size_t ws_size,
                              hipStream_t stream) {
  const float* q    = (const float*)d_in[0];
  const float* k    = (const float*)d_in[1];
  const float* v    = (const float*)d_in[2];
  const float* W    = (const float*)d_in[3];
  const float* bias = (const float*)d_in[4];
  float* out  = (float*)d_out;
  float* attn = out + (size_t)B_ * N_ * DIM_;      // outputs: [out | attn]
  float* ao   = (float*)d_ws;                      // (B*N, DIM) f32 pre-projection

  attn_kernel<<<B_ * H_ * (N_ / 64), 512, 0, stream>>>(q, k, v, attn, ao);
  proj_kernel<<<(B_ * N_ / 128) * (DIM_ / 128), 512, 0, stream>>>(ao, W, bias, out);
}

// Round 2
// 377.125 us; speedup vs baseline: 1.2879x; 1.2879x over previous
//
#include <hip/hip_runtime.h>

typedef __bf16 bf16x8 __attribute__((ext_vector_type(8)));
typedef unsigned short u16x8 __attribute__((ext_vector_type(8)));
typedef unsigned short u16x4 __attribute__((ext_vector_type(4)));
typedef float f32x4 __attribute__((ext_vector_type(4)));

#define B_    8
#define N_    1024
#define DIM_  1024
#define H_    8
#define HD_   128
#define SCALE_ 0.08838834764831845f

__device__ __forceinline__ unsigned short f2bf(float x) {
  unsigned int u = __float_as_uint(x);
  u += 0x7fffu + ((u >> 16) & 1u);           // RNE
  return (unsigned short)(u >> 16);
}
__device__ __forceinline__ float bf2f(unsigned short h) {
  return __uint_as_float(((unsigned int)h) << 16);
}
__device__ __forceinline__ f32x4 mfma16(u16x8 a, u16x8 b, f32x4 c) {
  return __builtin_amdgcn_mfma_f32_16x16x32_bf16(
      __builtin_bit_cast(bf16x8, a), __builtin_bit_cast(bf16x8, b), c, 0, 0, 0);
}
// plain barrier with compiler memory fences (no vmcnt drain!)
__device__ __forceinline__ void bar() {
  asm volatile("" ::: "memory");
  __builtin_amdgcn_s_barrier();
  asm volatile("" ::: "memory");
}
// publish LDS writes, then barrier
__device__ __forceinline__ void barpub() {
  asm volatile("s_waitcnt lgkmcnt(0)" ::: "memory");
  __builtin_amdgcn_sched_barrier(0);
  __builtin_amdgcn_s_barrier();
  asm volatile("" ::: "memory");
}

struct K1Smem {
  unsigned short p[64 * 1024];            // 131072 B: p[row][key] bf16, byte ^ ((row&7)<<4)
  union {
    unsigned short kbuf[64 * 2 * 128];    // 32768 B: [key][hl][d], byte = key*512+hl*256+(d*2 ^ ((key&7)<<4))
    float partial[4][64];                 // 1024 B
    unsigned short vt[2 * 2 * 128 * 32];  // 32768 B: [buf][hl]; off = (d*64+k*2) ^ ((d&7)<<4)
  } u;
};

__global__ __launch_bounds__(512, 2)
void attn_kernel(const float* __restrict__ gq, const float* __restrict__ gk,
                 const float* __restrict__ gv, float* __restrict__ gattn,
                 float* __restrict__ gao) {
  __shared__ K1Smem sm;
  const int bid = blockIdx.x;
  // XCD swizzle: same (b,h) q-tiles grouped per XCD, 2 bh-pairs per resident window
  const int xcd = bid & 7, slot = bid >> 3;
  const int bh = xcd + 8 * (slot >> 4);
  const int qt = slot & 15;
  const int bb = bh >> 3, hh = bh & 7;

  const int tid = threadIdx.x;
  const int wid = tid >> 6, lane = tid & 63;
  const int rg = wid >> 2;                   // 0..1: row half (32 rows)
  const int kg = wid & 3;                    // 0..3: key group (QK) / d group (PV)
  const int l15 = lane & 15, l4 = lane >> 4;

  // ---------------- Q fragments (pre-scaled, hi/lo split) ----------------
  u16x8 qhi[2][4], qlo[2][4];
  #pragma unroll
  for (int rt = 0; rt < 2; ++rt) {
    const int qrow = qt * 64 + rg * 32 + rt * 16 + l15;
    const float* qp = gq + ((size_t)bb * N_ + qrow) * DIM_ + hh * HD_;
    #pragma unroll
    for (int t = 0; t < 4; ++t) {
      const int d0 = t * 32 + l4 * 8;
      f32x4 f0 = *(const f32x4*)(qp + d0);
      f32x4 f1 = *(const f32x4*)(qp + d0 + 4);
      #pragma unroll
      for (int j = 0; j < 8; ++j) {
        float x = (j < 4 ? f0[j] : f1[j - 4]) * SCALE_;
        unsigned short hi = f2bf(x);
        qhi[rt][t][j] = hi;
        qlo[rt][t][j] = f2bf(x - bf2f(hi));
      }
    }
  }

  // ---------------- K staging helpers (reg-staged, T14 split) ----------------
  const int skey = tid >> 3;                 // 0..63
  const int sdq = (tid & 7) * 16;            // 0..112
  const float* kgbase = gk + (size_t)bb * N_ * DIM_ + hh * HD_ + sdq;
  f32x4 kst[4];
  auto loadK = [&](int it) {
    const float* p0 = kgbase + (size_t)(it * 64 + skey) * DIM_;
    #pragma unroll
    for (int j = 0; j < 4; ++j) kst[j] = *(const f32x4*)(p0 + j * 4);
  };
  auto writeK = [&]() {
    char* rowp = (char*)sm.u.kbuf + skey * 512;
    const int swz = (skey & 7) << 4;
    #pragma unroll
    for (int half = 0; half < 2; ++half) {
      u16x8 hi8, lo8;
      #pragma unroll
      for (int j = 0; j < 8; ++j) {
        float x = kst[half * 2 + (j >> 2)][j & 3];
        unsigned short h = f2bf(x);
        hi8[j] = h;
        lo8[j] = f2bf(x - bf2f(h));
      }
      const int off = (sdq * 2 + half * 16) ^ swz;
      *(u16x8*)(rowp + off) = hi8;
      *(u16x8*)(rowp + 256 + off) = lo8;
    }
  };

  // ---------------- Phase 1: S = Q K^T (bf16x3), p = exp(S) -> LDS ----------------
  float lsum[2][4] = {{0.f, 0.f, 0.f, 0.f}, {0.f, 0.f, 0.f, 0.f}};
  const int key16 = kg * 16 + l15;
  const char* krow = (const char*)sm.u.kbuf + key16 * 512;
  const int kswz = (key16 & 7) << 4;

  loadK(0);
  writeK();
  barpub();
  #pragma unroll 1
  for (int it = 0; it < 16; ++it) {
    if (it < 15) loadK(it + 1);              // issue early — lands during MFMA region
    u16x8 khi[4], klo[4];
    #pragma unroll
    for (int t = 0; t < 4; ++t) {
      const int off = (t * 64 + l4 * 16) ^ kswz;
      khi[t] = *(const u16x8*)(krow + off);
      klo[t] = *(const u16x8*)(krow + 256 + off);
    }
    f32x4 a0[2], a1[2], a2[2];
    #pragma unroll
    for (int rt = 0; rt < 2; ++rt) {
      a0[rt] = f32x4{0.f, 0.f, 0.f, 0.f};
      a1[rt] = f32x4{0.f, 0.f, 0.f, 0.f};
      a2[rt] = f32x4{0.f, 0.f, 0.f, 0.f};
    }
    #pragma unroll
    for (int t = 0; t < 4; ++t)
      #pragma unroll
      for (int rt = 0; rt < 2; ++rt) {
        a0[rt] = mfma16(qhi[rt][t], khi[t], a0[rt]);
        a1[rt] = mfma16(qhi[rt][t], klo[t], a1[rt]);
        a2[rt] = mfma16(qlo[rt][t], khi[t], a2[rt]);
      }
    const int keyg = it * 64 + kg * 16 + l15;
    #pragma unroll
    for (int rt = 0; rt < 2; ++rt) {
      #pragma unroll
      for (int r = 0; r < 4; ++r) {
        const int row = rg * 32 + rt * 16 + l4 * 4 + r;
        float s = (a0[rt][r] + a1[rt][r]) + a2[rt][r];
        s = fminf(s, 60.0f);
        float p = __expf(s);
        lsum[rt][r] += p;
        *(unsigned short*)((char*)sm.p + ((row * 2048 + keyg * 2) ^ ((row & 7) << 4))) = f2bf(p);
      }
    }
    bar();                                    // kbuf readers done
    if (it < 15) writeK();                    // vmcnt dep-wait on kst handled by compiler
    barpub();                                 // publish kbuf (and p so far)
  }

  // ---------------- V staging helpers ----------------
  const bool stager = (tid < 256);
  const int vkey4 = (tid & 7) * 4;            // 0..28
  const int vd0 = ((tid & 255) >> 3) * 4;     // 0..124
  f32x4 vst[4];
  auto loadV = [&](int kt) {
    const float* p0 = gv + ((size_t)bb * N_ + kt * 32 + vkey4) * DIM_ + hh * HD_ + vd0;
    #pragma unroll
    for (int j = 0; j < 4; ++j) vst[j] = *(const f32x4*)(p0 + (size_t)j * DIM_);
  };
  auto writeV = [&](int buf) {
    char* base = (char*)sm.u.vt + buf * 16384;
    #pragma unroll
    for (int dd = 0; dd < 4; ++dd) {
      const int d = vd0 + dd;
      u16x4 h4, g4;
      #pragma unroll
      for (int j = 0; j < 4; ++j) {
        float x = vst[j][dd];
        unsigned short h = f2bf(x);
        h4[j] = h;
        g4[j] = f2bf(x - bf2f(h));
      }
      const int off = (d * 64 + vkey4 * 2) ^ ((d & 7) << 4);
      *(u16x4*)(base + off) = h4;
      *(u16x4*)(base + 8192 + off) = g4;
    }
  };

  // ---------------- rowsums -> partial -> rinv ----------------
  if (stager) loadV(0);                       // overlap V0 load with reduction
  #pragma unroll
  for (int rt = 0; rt < 2; ++rt)
    #pragma unroll
    for (int r = 0; r < 4; ++r) {
      float s = lsum[rt][r];
      s += __shfl_xor(s, 1); s += __shfl_xor(s, 2);
      s += __shfl_xor(s, 4); s += __shfl_xor(s, 8);
      lsum[rt][r] = s;
    }
  if (l15 == 0) {
    #pragma unroll
    for (int rt = 0; rt < 2; ++rt)
      #pragma unroll
      for (int r = 0; r < 4; ++r)
        sm.u.partial[kg][rg * 32 + rt * 16 + l4 * 4 + r] = lsum[rt][r];
  }
  barpub();
  float rvf[2][4];
  #pragma unroll
  for (int rt = 0; rt < 2; ++rt)
    #pragma unroll
    for (int r = 0; r < 4; ++r) {
      const int row = rg * 32 + rt * 16 + l4 * 4 + r;
      rvf[rt][r] = 1.0f / (sm.u.partial[0][row] + sm.u.partial[1][row] +
                           sm.u.partial[2][row] + sm.u.partial[3][row]);
    }
  const int srow = tid >> 3;
  const float rvs = 1.0f / (sm.u.partial[0][srow] + sm.u.partial[1][srow] +
                            sm.u.partial[2][srow] + sm.u.partial[3][srow]);
  bar();                                      // partial readers done before vt overwrite
  if (stager) writeV(0);
  barpub();

  // ---------------- Phase 2: PV (double-buffered vt) + fused attn write ----------------
  f32x4 oacc[2][2];
  #pragma unroll
  for (int rt = 0; rt < 2; ++rt)
    #pragma unroll
    for (int ct = 0; ct < 2; ++ct) oacc[rt][ct] = f32x4{0.f, 0.f, 0.f, 0.f};

  float* abase = gattn + (((size_t)(bb * 8 + hh)) * N_ + qt * 64 + srow) * N_ + (tid & 7) * 4;
  const char* prow_store = (const char*)sm.p + srow * 2048;
  const int sswz = (srow & 7) << 4;
  const int dw = kg;
  int cur = 0;
  #pragma unroll 1
  for (int kt = 0; kt < 32; ++kt) {
    if (stager && kt < 31) loadV(kt + 1);     // issue early
    const char* vbase = (const char*)sm.u.vt + cur * 16384;
    u16x8 vh[2], vl[2];
    #pragma unroll
    for (int ct = 0; ct < 2; ++ct) {
      const int d = dw * 32 + ct * 16 + l15;
      const int off = (d * 64 + l4 * 16) ^ ((d & 7) << 4);
      vh[ct] = *(const u16x8*)(vbase + off);
      vl[ct] = *(const u16x8*)(vbase + 8192 + off);
    }
    #pragma unroll
    for (int rt = 0; rt < 2; ++rt) {
      const int prow = rg * 32 + rt * 16 + l15;
      u16x8 pa = *(const u16x8*)((const char*)sm.p + prow * 2048 +
                                 ((kt * 64 + l4 * 16) ^ ((prow & 7) << 4)));
      #pragma unroll
      for (int ct = 0; ct < 2; ++ct) {
        oacc[rt][ct] = mfma16(pa, vh[ct], oacc[rt][ct]);
        oacc[rt][ct] = mfma16(pa, vl[ct], oacc[rt][ct]);
      }
    }
    // fused attn write: 64 rows x 32 keys this iter (fire-and-forget stores)
    {
      unsigned long long pw = *(const unsigned long long*)
          (prow_store + ((kt * 64 + (tid & 7) * 8) ^ sswz));
      f32x4 o;
      o[0] = bf2f((unsigned short)(pw      )) * rvs;
      o[1] = bf2f((unsigned short)(pw >> 16)) * rvs;
      o[2] = bf2f((unsigned short)(pw >> 32)) * rvs;
      o[3] = bf2f((unsigned short)(pw >> 48)) * rvs;
      *(f32x4*)(abase + kt * 32) = o;
    }
    if (stager && kt < 31) writeV(cur ^ 1);   // write NEXT buffer — no mid barrier needed
    barpub();
    cur ^= 1;
  }

  // ---------------- epilogue: ao = (PV) * rinv ----------------
  #pragma unroll
  for (int rt = 0; rt < 2; ++rt)
    #pragma unroll
    for (int ct = 0; ct < 2; ++ct) {
      const int d = dw * 32 + ct * 16 + l15;
      float* dst = gao + ((size_t)bb * N_ + qt * 64 + rg * 32 + rt * 16 + l4 * 4) * DIM_ +
                   hh * HD_ + d;
      #pragma unroll
      for (int r = 0; r < 4; ++r)
        dst[(size_t)r * DIM_] = oacc[rt][ct][r] * rvf[rt][r];
    }
}

// ---------------- K2: out = ao @ W^T + b  (bf16x3, 128x128 tiles) ----------------
__device__ __forceinline__ void pack_store(char* rowbase, int swz, int hl_off,
                                           int kp, float x0, float x1, float x2, float x3) {
  unsigned short h0 = f2bf(x0), h1 = f2bf(x1), h2 = f2bf(x2), h3 = f2bf(x3);
  unsigned short g0 = f2bf(x0 - bf2f(h0)), g1 = f2bf(x1 - bf2f(h1));
  unsigned short g2 = f2bf(x2 - bf2f(h2)), g3 = f2bf(x3 - bf2f(h3));
  *(unsigned int*)(rowbase + ((kp * 2) ^ swz))              = (unsigned int)h0 | ((unsigned int)h1 << 16);
  *(unsigned int*)(rowbase + ((kp * 2 + 4) ^ swz))          = (unsigned int)h2 | ((unsigned int)h3 << 16);
  *(unsigned int*)(rowbase + ((hl_off + kp * 2) ^ swz))     = (unsigned int)g0 | ((unsigned int)g1 << 16);
  *(unsigned int*)(rowbase + ((hl_off + kp * 2 + 4) ^ swz)) = (unsigned int)g2 | ((unsigned int)g3 << 16);
}

struct K2Smem {
  unsigned short A[128 * 2 * 32];
  unsigned short Bm[128 * 2 * 32];
};

__global__ __launch_bounds__(512)
void proj_kernel(const float* __restrict__ gao, const float* __restrict__ gw,
                 const float* __restrict__ gbias, float* __restrict__ gout) {
  __shared__ K2Smem sm;
  const int bid = blockIdx.x;
  const int mt = bid >> 3, nt = bid & 7;
  const int m0 = mt * 128, n0 = nt * 128;
  const int tid = threadIdx.x;
  const int wid = tid >> 6, lane = tid & 63;
  const int wr = wid >> 1, wc = wid & 1;
  const int l15 = lane & 15, l4 = lane >> 4;

  f32x4 acc[2][4];
  #pragma unroll
  for (int i = 0; i < 2; ++i)
    #pragma unroll
    for (int j = 0; j < 4; ++j) acc[i][j] = f32x4{0.f, 0.f, 0.f, 0.f};

  #pragma unroll 1
  for (int step = 0; step < 32; ++step) {
    const int k0 = step * 32;
    if (step) __syncthreads();
    #pragma unroll
    for (int c0 = 0; c0 < 2; ++c0) {
      const int c = tid + 512 * c0;
      const int row = c >> 3;
      const int kp = (c & 7) * 4;
      f32x4 fa = *(const f32x4*)(gao + (size_t)(m0 + row) * DIM_ + k0 + kp);
      f32x4 fb = *(const f32x4*)(gw + (size_t)(n0 + row) * DIM_ + k0 + kp);
      const int swz = (row & 7) << 4;
      pack_store((char*)sm.A + row * 128, swz, 64, kp, fa[0], fa[1], fa[2], fa[3]);
      pack_store((char*)sm.Bm + row * 128, swz, 64, kp, fb[0], fb[1], fb[2], fb[3]);
    }
    __syncthreads();

    u16x8 ah[2], al[2], bh[4], bl[4];
    #pragma unroll
    for (int t = 0; t < 2; ++t) {
      const int row = wr * 32 + t * 16 + l15;
      const char* rp = (char*)sm.A + row * 128;
      const int swz = (row & 7) << 4;
      ah[t] = *(const u16x8*)(rp + ((l4 * 16) ^ swz));
      al[t] = *(const u16x8*)(rp + ((64 + l4 * 16) ^ swz));
    }
    #pragma unroll
    for (int t = 0; t < 4; ++t) {
      const int col = wc * 64 + t * 16 + l15;
      const char* rp = (char*)sm.Bm + col * 128;
      const int swz = (col & 7) << 4;
      bh[t] = *(const u16x8*)(rp + ((l4 * 16) ^ swz));
      bl[t] = *(const u16x8*)(rp + ((64 + l4 * 16) ^ swz));
    }
    #pragma unroll
    for (int i = 0; i < 2; ++i)
      #pragma unroll
      for (int j = 0; j < 4; ++j)
        acc[i][j] = mfma16(ah[i], bh[j], acc[i][j]);
    #pragma unroll
    for (int i = 0; i < 2; ++i)
      #pragma unroll
      for (int j = 0; j < 4; ++j)
        acc[i][j] = mfma16(ah[i], bl[j], acc[i][j]);
    #pragma unroll
    for (int i = 0; i < 2; ++i)
      #pragma unroll
      for (int j = 0; j < 4; ++j)
        acc[i][j] = mfma16(al[i], bh[j], acc[i][j]);
  }

  #pragma unroll
  for (int i = 0; i < 2; ++i) {
    #pragma unroll
    for (int j = 0; j < 4; ++j) {
      const int col = n0 + wc * 64 + j * 16 + l15;
      const float bv = gbias[col];
      float* dst = gout + (size_t)(m0 + wr * 32 + i * 16 + l4 * 4) * DIM_ + col;
      #pragma unroll
      for (int r = 0; r < 4; ++r)
        dst[(size_t)r * DIM_] = acc[i][j][r] + bv;
    }
  }
}

extern "C" void kernel_launch(void* const* d_in, const int* in_sizes, int n_in,
                              void* d_out, int out_size, void* d_ws, size_t ws_size,
                              hipStream_t stream) {
  const float* q    = (const float*)d_in[0];
  const float* k    = (const float*)d_in[1];
  const float* v    = (const float*)d_in[2];
  const float* W    = (const float*)d_in[3];
  const float* bias = (const float*)d_in[4];
  float* out  = (float*)d_out;
  float* attn = out + (size_t)B_ * N_ * DIM_;      // outputs: [out | attn]
  float* ao   = (float*)d_ws;                      // (B*N, DIM) f32 pre-projection

  attn_kernel<<<B_ * H_ * (N_ / 64), 512, 0, stream>>>(q, k, v, attn, ao);
  proj_kernel<<<(B_ * N_ / 128) * (DIM_ / 128), 512, 0, stream>>>(ao, W, bias, out);
}

// Round 3
// 297.575 us; speedup vs baseline: 1.6322x; 1.2673x over previous
//
#include <hip/hip_runtime.h>

typedef __bf16 bf16x8 __attribute__((ext_vector_type(8)));
typedef unsigned short u16x8 __attribute__((ext_vector_type(8)));
typedef unsigned short u16x4 __attribute__((ext_vector_type(4)));
typedef float f32x4 __attribute__((ext_vector_type(4)));

#define B_    8
#define N_    1024
#define DIM_  1024
#define H_    8
#define HD_   128
#define SCALE_ 0.08838834764831845f

__device__ __forceinline__ unsigned short f2bf(float x) {
  unsigned int u = __float_as_uint(x);
  u += 0x7fffu + ((u >> 16) & 1u);           // RNE
  return (unsigned short)(u >> 16);
}
__device__ __forceinline__ float bf2f(unsigned short h) {
  return __uint_as_float(((unsigned int)h) << 16);
}
__device__ __forceinline__ f32x4 mfma16(u16x8 a, u16x8 b, f32x4 c) {
  return __builtin_amdgcn_mfma_f32_16x16x32_bf16(
      __builtin_bit_cast(bf16x8, a), __builtin_bit_cast(bf16x8, b), c, 0, 0, 0);
}
// async global->LDS, 16B per lane; lds dest must be wave-uniform (HW adds lane*16)
__device__ __forceinline__ void gl_lds16(const void* g, void* l) {
  __builtin_amdgcn_global_load_lds(
      (const __attribute__((address_space(1))) unsigned int*)g,
      (__attribute__((address_space(3))) unsigned int*)l, 16, 0, 0);
}
#define SBAR() do { asm volatile("" ::: "memory"); __builtin_amdgcn_s_barrier(); \
                    asm volatile("" ::: "memory"); } while (0)
#define LGKM0() do { asm volatile("s_waitcnt lgkmcnt(0)" ::: "memory"); \
                     __builtin_amdgcn_sched_barrier(0); } while (0)
#define VM0()   asm volatile("s_waitcnt vmcnt(0)" ::: "memory")

// ---------------- workspace layout (bytes) ----------------
// kimg 32MB | vimg 32MB | whi 2MB | wlo 2MB | aohi 16MB | aolo 16MB = 100MB
#define WS_KIMG  0
#define WS_VIMG  33554432
#define WS_WHI   67108864
#define WS_WLO   69206016
#define WS_AOHI  71303168
#define WS_AOLO  88080384

// ================= prep kernels: one-time f32 -> bf16 hi/lo images =================
// K image per (bh, ktile of 64 keys): 32KB = [key 0..63][hi 256B | lo 256B],
// within row: byte (d*2) ^ ((key&7)<<4)
__global__ __launch_bounds__(256)
void prep_k(const float* __restrict__ gk, char* __restrict__ kimg) {
  const int blk = blockIdx.x;                // bh*16 + kt
  const int bh = blk >> 4, kt = blk & 15;
  const int bb = bh >> 3, hh = bh & 7;
  const int t = threadIdx.x;
  char* base = kimg + (size_t)bh * 524288 + kt * 32768;
  const float* src = gk + ((size_t)bb * N_ + kt * 64) * DIM_ + hh * HD_;
  #pragma unroll
  for (int c = 0; c < 8; ++c) {
    const int idx = t + 256 * c;
    const int key = idx >> 5, dq = (idx & 31) * 4;
    f32x4 f = *(const f32x4*)(src + (size_t)key * DIM_ + dq);
    u16x4 h, g;
    #pragma unroll
    for (int j = 0; j < 4; ++j) {
      unsigned short hv = f2bf(f[j]);
      h[j] = hv;
      g[j] = f2bf(f[j] - bf2f(hv));
    }
    const int off = (dq * 2) ^ ((key & 7) << 4);
    *(u16x4*)(base + key * 512 + off) = h;
    *(u16x4*)(base + key * 512 + 256 + off) = g;
  }
}

// V image per (bh, vtile of 32 keys): 16KB = [hi 8KB | lo 8KB],
// plane byte: (d*64 + key*2) ^ ((d&7)<<4)   (d-major: transposed)
__global__ __launch_bounds__(256)
void prep_v(const float* __restrict__ gv, char* __restrict__ vimg) {
  __shared__ float tile[32][132];
  const int blk = blockIdx.x;                // bh*32 + kt
  const int bh = blk >> 5, kt = blk & 31;
  const int bb = bh >> 3, hh = bh & 7;
  const int t = threadIdx.x;
  const float* src = gv + ((size_t)bb * N_ + kt * 32) * DIM_ + hh * HD_;
  #pragma unroll
  for (int c = 0; c < 4; ++c) {
    const int idx = t + 256 * c;
    const int key = idx >> 5, dq = (idx & 31) * 4;
    *(f32x4*)&tile[key][dq] = *(const f32x4*)(src + (size_t)key * DIM_ + dq);
  }
  __syncthreads();
  char* base = vimg + (size_t)bh * 524288 + kt * 16384;
  #pragma unroll
  for (int c = 0; c < 2; ++c) {
    const int oc = t + 256 * c;              // 0..511
    const int d = oc >> 2, kc = oc & 3;
    u16x8 h, g;
    #pragma unroll
    for (int j = 0; j < 8; ++j) {
      float x = tile[kc * 8 + j][d];
      unsigned short hv = f2bf(x);
      h[j] = hv;
      g[j] = f2bf(x - bf2f(hv));
    }
    const int off = (d * 64 + kc * 16) ^ ((d & 7) << 4);
    *(u16x8*)(base + off) = h;
    *(u16x8*)(base + 8192 + off) = g;
  }
}

// W planes: plain row-major bf16 hi/lo [1024][1024]
__global__ __launch_bounds__(256)
void prep_w(const float* __restrict__ gw, unsigned short* __restrict__ whi,
            unsigned short* __restrict__ wlo) {
  const int idx = blockIdx.x * 256 + threadIdx.x;  // 0..131071
  const int row = idx >> 7, k0 = (idx & 127) * 8;
  const float* s = gw + (size_t)row * DIM_ + k0;
  f32x4 f0 = *(const f32x4*)s;
  f32x4 f1 = *(const f32x4*)(s + 4);
  u16x8 h, g;
  #pragma unroll
  for (int j = 0; j < 8; ++j) {
    float x = j < 4 ? f0[j] : f1[j - 4];
    unsigned short hv = f2bf(x);
    h[j] = hv;
    g[j] = f2bf(x - bf2f(hv));
  }
  *(u16x8*)(whi + (size_t)row * DIM_ + k0) = h;
  *(u16x8*)(wlo + (size_t)row * DIM_ + k0) = g;
}

// ================= attention kernel =================
struct K1Smem {
  unsigned short p[64 * 1024];            // 131072 B: p[row][key] bf16, byte ^ ((row&7)<<4)
  union {
    char kbuf[32768];                     // K tile image (64 keys)
    char vt[2][16384];                    // V tile images (dbuf, 32 keys each)
    struct { char pad[16384]; float partial[4][64]; } pp;
  } u;
};

__global__ __launch_bounds__(512, 2)
void attn_kernel(const float* __restrict__ gq, const char* __restrict__ kimg,
                 const char* __restrict__ vimg, float* __restrict__ gattn,
                 unsigned short* __restrict__ aohi, unsigned short* __restrict__ aolo) {
  __shared__ K1Smem sm;
  const int bid = blockIdx.x;
  // XCD swizzle: 16 q-tiles of one (b,h) share an XCD (bid%8 = XCD)
  const int xcd = bid & 7, slot = bid >> 3;
  const int bh = xcd + 8 * (slot >> 4);
  const int qt = slot & 15;
  const int bb = bh >> 3, hh = bh & 7;

  const int tid = threadIdx.x;
  const int wid = tid >> 6, lane = tid & 63;
  const int rg = wid >> 2;                   // 0..1: row half
  const int kg = wid & 3;                    // 0..3: key group (QK) / d group (PV)
  const int l15 = lane & 15, l4 = lane >> 4;

  const char* kimg_bh = kimg + (size_t)bh * 524288;
  const char* vimg_bh = vimg + (size_t)bh * 524288;
  char* const kb = sm.u.kbuf;

  auto issueK = [&](int it) {
    const char* s = kimg_bh + it * 32768 + wid * 4096 + lane * 16;
    char* d = kb + wid * 4096;
    #pragma unroll
    for (int c = 0; c < 4; ++c) gl_lds16(s + c * 1024, d + c * 1024);
  };
  auto issueV = [&](int kt, int buf) {
    const char* s = vimg_bh + kt * 16384 + wid * 2048 + lane * 16;
    char* d = sm.u.vt[buf] + wid * 2048;
    #pragma unroll
    for (int c = 0; c < 2; ++c) gl_lds16(s + c * 1024, d + c * 1024);
  };

  issueK(0);                                 // K0 flies while we convert Q

  // ---------------- Q fragments (pre-scaled, hi/lo split) ----------------
  u16x8 qhi[2][4], qlo[2][4];
  #pragma unroll
  for (int rt = 0; rt < 2; ++rt) {
    const int qrow = qt * 64 + rg * 32 + rt * 16 + l15;
    const float* qp = gq + ((size_t)bb * N_ + qrow) * DIM_ + hh * HD_;
    #pragma unroll
    for (int t = 0; t < 4; ++t) {
      const int d0 = t * 32 + l4 * 8;
      f32x4 f0 = *(const f32x4*)(qp + d0);
      f32x4 f1 = *(const f32x4*)(qp + d0 + 4);
      #pragma unroll
      for (int j = 0; j < 8; ++j) {
        float x = (j < 4 ? f0[j] : f1[j - 4]) * SCALE_;
        unsigned short hi = f2bf(x);
        qhi[rt][t][j] = hi;
        qlo[rt][t][j] = f2bf(x - bf2f(hi));
      }
    }
  }

  // ---------------- Phase 1: S = Q K^T (bf16x3), p = exp(S) -> LDS ----------------
  float lsum[2][4] = {{0.f, 0.f, 0.f, 0.f}, {0.f, 0.f, 0.f, 0.f}};
  const int key16 = kg * 16 + l15;
  const char* krow = kb + key16 * 512;
  const int kswz = (key16 & 7) << 4;

  VM0();
  SBAR();                                    // kbuf[0] ready
  #pragma unroll 1
  for (int it = 0; it < 16; ++it) {
    u16x8 khi[4], klo[4];
    #pragma unroll
    for (int t = 0; t < 4; ++t) {
      const int off = (t * 64 + l4 * 16) ^ kswz;
      khi[t] = *(const u16x8*)(krow + off);
      klo[t] = *(const u16x8*)(krow + 256 + off);
    }
    LGKM0();
    SBAR();                                  // all kbuf readers have their regs
    if (it < 15) issueK(it + 1);             // lands during MFMA+exp below

    f32x4 a0[2], a1[2], a2[2];
    #pragma unroll
    for (int rt = 0; rt < 2; ++rt) {
      a0[rt] = f32x4{0.f, 0.f, 0.f, 0.f};
      a1[rt] = f32x4{0.f, 0.f, 0.f, 0.f};
      a2[rt] = f32x4{0.f, 0.f, 0.f, 0.f};
    }
    #pragma unroll
    for (int t = 0; t < 4; ++t)
      #pragma unroll
      for (int rt = 0; rt < 2; ++rt) {
        a0[rt] = mfma16(qhi[rt][t], khi[t], a0[rt]);
        a1[rt] = mfma16(qhi[rt][t], klo[t], a1[rt]);
        a2[rt] = mfma16(qlo[rt][t], khi[t], a2[rt]);
      }
    const int keyg = it * 64 + kg * 16 + l15;
    #pragma unroll
    for (int rt = 0; rt < 2; ++rt) {
      #pragma unroll
      for (int r = 0; r < 4; ++r) {
        const int row = rg * 32 + rt * 16 + l4 * 4 + r;
        float s = (a0[rt][r] + a1[rt][r]) + a2[rt][r];
        s = fminf(s, 60.0f);
        float p = __expf(s);
        lsum[rt][r] += p;
        *(unsigned short*)((char*)sm.p + ((row * 2048 + keyg * 2) ^ ((row & 7) << 4))) = f2bf(p);
      }
    }
    if (it < 15) VM0();                      // next K tile landed (hid under compute)
    SBAR();
  }

  // ---------------- rowsums -> partial -> rinv; V0 in flight ----------------
  issueV(0, 0);                              // vt[0] aliases dead kbuf bytes
  #pragma unroll
  for (int rt = 0; rt < 2; ++rt)
    #pragma unroll
    for (int r = 0; r < 4; ++r) {
      float s = lsum[rt][r];
      s += __shfl_xor(s, 1); s += __shfl_xor(s, 2);
      s += __shfl_xor(s, 4); s += __shfl_xor(s, 8);
      lsum[rt][r] = s;
    }
  if (l15 == 0) {
    #pragma unroll
    for (int rt = 0; rt < 2; ++rt)
      #pragma unroll
      for (int r = 0; r < 4; ++r)
        sm.u.pp.partial[kg][rg * 32 + rt * 16 + l4 * 4 + r] = lsum[rt][r];
  }
  LGKM0();
  SBAR();
  float rvf[2][4];
  #pragma unroll
  for (int rt = 0; rt < 2; ++rt)
    #pragma unroll
    for (int r = 0; r < 4; ++r) {
      const int row = rg * 32 + rt * 16 + l4 * 4 + r;
      rvf[rt][r] = 1.0f / (sm.u.pp.partial[0][row] + sm.u.pp.partial[1][row] +
                           sm.u.pp.partial[2][row] + sm.u.pp.partial[3][row]);
    }
  const int srow = tid >> 3;
  const float rvs = 1.0f / (sm.u.pp.partial[0][srow] + sm.u.pp.partial[1][srow] +
                            sm.u.pp.partial[2][srow] + sm.u.pp.partial[3][srow]);
  VM0();                                     // vt[0] loaded
  SBAR();                                    // partial reads done -> vt[1] free

  // ---------------- Phase 2: PV (dbuf vt) + fused normalized attn write ----------------
  f32x4 oacc[2][2];
  #pragma unroll
  for (int rt = 0; rt < 2; ++rt)
    #pragma unroll
    for (int ct = 0; ct < 2; ++ct) oacc[rt][ct] = f32x4{0.f, 0.f, 0.f, 0.f};

  float* abase = gattn + (((size_t)(bb * 8 + hh)) * N_ + qt * 64 + srow) * N_ + (tid & 7) * 4;
  const char* prow_store = (const char*)sm.p + srow * 2048;
  const int sswz = (srow & 7) << 4;
  const int dw = kg;
  int cur = 0;
  #pragma unroll 1
  for (int kt = 0; kt < 32; ++kt) {
    if (kt < 31) issueV(kt + 1, cur ^ 1);
    const char* vbase = sm.u.vt[cur];
    u16x8 vh[2], vl[2];
    #pragma unroll
    for (int ct = 0; ct < 2; ++ct) {
      const int d = dw * 32 + ct * 16 + l15;
      const int off = (d * 64 + l4 * 16) ^ ((d & 7) << 4);
      vh[ct] = *(const u16x8*)(vbase + off);
      vl[ct] = *(const u16x8*)(vbase + 8192 + off);
    }
    #pragma unroll
    for (int rt = 0; rt < 2; ++rt) {
      const int prow = rg * 32 + rt * 16 + l15;
      u16x8 pa = *(const u16x8*)((const char*)sm.p + prow * 2048 +
                                 ((kt * 64 + l4 * 16) ^ ((prow & 7) << 4)));
      #pragma unroll
      for (int ct = 0; ct < 2; ++ct) {
        oacc[rt][ct] = mfma16(pa, vh[ct], oacc[rt][ct]);
        oacc[rt][ct] = mfma16(pa, vl[ct], oacc[rt][ct]);
      }
    }
    // fused attn write: 64 rows x 32 keys (nontemporal, fire-and-forget)
    {
      unsigned long long pw = *(const unsigned long long*)
          (prow_store + ((kt * 64 + (tid & 7) * 8) ^ sswz));
      f32x4 o;
      o[0] = bf2f((unsigned short)(pw      )) * rvs;
      o[1] = bf2f((unsigned short)(pw >> 16)) * rvs;
      o[2] = bf2f((unsigned short)(pw >> 32)) * rvs;
      o[3] = bf2f((unsigned short)(pw >> 48)) * rvs;
      __builtin_nontemporal_store(o, (f32x4*)(abase + kt * 32));
    }
    LGKM0();                                 // vt/p reads drained before buffer swap
    if (kt < 31) VM0();                      // next V landed
    SBAR();
    cur ^= 1;
  }

  // ---------------- epilogue: ao = (PV)*rinv as bf16 hi/lo planes ----------------
  #pragma unroll
  for (int rt = 0; rt < 2; ++rt)
    #pragma unroll
    for (int ct = 0; ct < 2; ++ct) {
      const int col = hh * HD_ + dw * 32 + ct * 16 + l15;
      const int row0 = bb * N_ + qt * 64 + rg * 32 + rt * 16 + l4 * 4;
      #pragma unroll
      for (int r = 0; r < 4; ++r) {
        float val = oacc[rt][ct][r] * rvf[rt][r];
        unsigned short hv = f2bf(val);
        unsigned short lv = f2bf(val - bf2f(hv));
        const size_t off = (size_t)(row0 + r) * DIM_ + col;
        __builtin_nontemporal_store(hv, aohi + off);
        __builtin_nontemporal_store(lv, aolo + off);
      }
    }
}

// ================= K2: out = ao @ W^T + b (bf16x3, pre-split operands) =================
struct K2Smem {
  unsigned short A[128 * 2 * 32];   // byte = row*128 + ((hl*64 + k*2) ^ ((row&7)<<4))
  unsigned short Bm[128 * 2 * 32];
};

__global__ __launch_bounds__(512)
void proj_kernel(const unsigned short* __restrict__ aohi, const unsigned short* __restrict__ aolo,
                 const unsigned short* __restrict__ whi, const unsigned short* __restrict__ wlo,
                 const float* __restrict__ gbias, float* __restrict__ gout) {
  __shared__ K2Smem sm;
  const int bid = blockIdx.x;
  const int mt = bid >> 3, nt = bid & 7;
  const int m0 = mt * 128, n0 = nt * 128;
  const int tid = threadIdx.x;
  const int wid = tid >> 6, lane = tid & 63;
  const int wr = wid >> 1, wc = wid & 1;
  const int l15 = lane & 15, l4 = lane >> 4;

  f32x4 acc[2][4];
  #pragma unroll
  for (int i = 0; i < 2; ++i)
    #pragma unroll
    for (int j = 0; j < 4; ++j) acc[i][j] = f32x4{0.f, 0.f, 0.f, 0.f};

  #pragma unroll 1
  for (int step = 0; step < 32; ++step) {
    const int k0 = step * 32;
    if (step) __syncthreads();
    #pragma unroll
    for (int c0 = 0; c0 < 4; ++c0) {
      const int c = tid + 512 * c0;          // 0..2047
      const int mat = c >> 10;               // 0:A 1:B
      const int cc = c & 1023;
      const int row = cc >> 3, hl = (cc >> 2) & 1, ch = cc & 3;
      const unsigned short* plane = mat == 0 ? (hl ? aolo : aohi) : (hl ? wlo : whi);
      const size_t grow = (size_t)((mat == 0 ? m0 : n0) + row);
      u16x8 vdat = *(const u16x8*)(plane + grow * DIM_ + k0 + ch * 8);
      char* lbase = (mat == 0 ? (char*)sm.A : (char*)sm.Bm) + row * 128;
      *(u16x8*)(lbase + ((hl * 64 + ch * 16) ^ ((row & 7) << 4))) = vdat;
    }
    __syncthreads();

    u16x8 ah[2], al[2], bh[4], bl[4];
    #pragma unroll
    for (int t = 0; t < 2; ++t) {
      const int row = wr * 32 + t * 16 + l15;
      const char* rp = (char*)sm.A + row * 128;
      const int swz = (row & 7) << 4;
      ah[t] = *(const u16x8*)(rp + ((l4 * 16) ^ swz));
      al[t] = *(const u16x8*)(rp + ((64 + l4 * 16) ^ swz));
    }
    #pragma unroll
    for (int t = 0; t < 4; ++t) {
      const int col = wc * 64 + t * 16 + l15;
      const char* rp = (char*)sm.Bm + col * 128;
      const int swz = (col & 7) << 4;
      bh[t] = *(const u16x8*)(rp + ((l4 * 16) ^ swz));
      bl[t] = *(const u16x8*)(rp + ((64 + l4 * 16) ^ swz));
    }
    #pragma unroll
    for (int i = 0; i < 2; ++i)
      #pragma unroll
      for (int j = 0; j < 4; ++j)
        acc[i][j] = mfma16(ah[i], bh[j], acc[i][j]);
    #pragma unroll
    for (int i = 0; i < 2; ++i)
      #pragma unroll
      for (int j = 0; j < 4; ++j)
        acc[i][j] = mfma16(ah[i], bl[j], acc[i][j]);
    #pragma unroll
    for (int i = 0; i < 2; ++i)
      #pragma unroll
      for (int j = 0; j < 4; ++j)
        acc[i][j] = mfma16(al[i], bh[j], acc[i][j]);
  }

  #pragma unroll
  for (int i = 0; i < 2; ++i) {
    #pragma unroll
    for (int j = 0; j < 4; ++j) {
      const int col = n0 + wc * 64 + j * 16 + l15;
      const float bv = gbias[col];
      float* dst = gout + (size_t)(m0 + wr * 32 + i * 16 + l4 * 4) * DIM_ + col;
      #pragma unroll
      for (int r = 0; r < 4; ++r)
        dst[(size_t)r * DIM_] = acc[i][j][r] + bv;
    }
  }
}

extern "C" void kernel_launch(void* const* d_in, const int* in_sizes, int n_in,
                              void* d_out, int out_size, void* d_ws, size_t ws_size,
                              hipStream_t stream) {
  const float* q    = (const float*)d_in[0];
  const float* k    = (const float*)d_in[1];
  const float* v    = (const float*)d_in[2];
  const float* W    = (const float*)d_in[3];
  const float* bias = (const float*)d_in[4];
  float* out  = (float*)d_out;
  float* attn = out + (size_t)B_ * N_ * DIM_;      // outputs: [out | attn]

  char* ws = (char*)d_ws;                          // needs 100 MB
  char* kimg = ws + WS_KIMG;
  char* vimg = ws + WS_VIMG;
  unsigned short* whi  = (unsigned short*)(ws + WS_WHI);
  unsigned short* wlo  = (unsigned short*)(ws + WS_WLO);
  unsigned short* aohi = (unsigned short*)(ws + WS_AOHI);
  unsigned short* aolo = (unsigned short*)(ws + WS_AOLO);

  prep_k<<<64 * 16, 256, 0, stream>>>(k, kimg);
  prep_v<<<64 * 32, 256, 0, stream>>>(v, vimg);
  prep_w<<<512, 256, 0, stream>>>(W, whi, wlo);
  attn_kernel<<<B_ * H_ * (N_ / 64), 512, 0, stream>>>(q, kimg, vimg, attn, aohi, aolo);
  proj_kernel<<<(B_ * N_ / 128) * (DIM_ / 128), 512, 0, stream>>>(aohi, aolo, whi, wlo, bias, out);
}

// Round 4
// 273.441 us; speedup vs baseline: 1.7763x; 1.0883x over previous
//
#include <hip/hip_runtime.h>

typedef __bf16 bf16x8 __attribute__((ext_vector_type(8)));
typedef unsigned short u16x8 __attribute__((ext_vector_type(8)));
typedef unsigned short u16x4 __attribute__((ext_vector_type(4)));
typedef float f32x4 __attribute__((ext_vector_type(4)));

#define B_    8
#define N_    1024
#define DIM_  1024
#define H_    8
#define HD_   128
#define SCALE_ 0.08838834764831845f

__device__ __forceinline__ unsigned short f2bf(float x) {
  unsigned int u = __float_as_uint(x);
  u += 0x7fffu + ((u >> 16) & 1u);           // RNE
  return (unsigned short)(u >> 16);
}
__device__ __forceinline__ float bf2f(unsigned short h) {
  return __uint_as_float(((unsigned int)h) << 16);
}
__device__ __forceinline__ f32x4 mfma16(u16x8 a, u16x8 b, f32x4 c) {
  return __builtin_amdgcn_mfma_f32_16x16x32_bf16(
      __builtin_bit_cast(bf16x8, a), __builtin_bit_cast(bf16x8, b), c, 0, 0, 0);
}
// async global->LDS, 16B per lane; lds dest is wave-uniform (HW adds lane*16)
__device__ __forceinline__ void gl_lds16(const void* g, void* l) {
  __builtin_amdgcn_global_load_lds(
      (const __attribute__((address_space(1))) unsigned int*)g,
      (__attribute__((address_space(3))) unsigned int*)l, 16, 0, 0);
}
#define SBAR() do { asm volatile("" ::: "memory"); __builtin_amdgcn_s_barrier(); \
                    asm volatile("" ::: "memory"); } while (0)
#define LGKM0() do { asm volatile("s_waitcnt lgkmcnt(0)" ::: "memory"); \
                     __builtin_amdgcn_sched_barrier(0); } while (0)

// ---------------- workspace layout (bytes) ----------------
#define WS_KIMG  0
#define WS_VIMG  33554432
#define WS_WHI   67108864
#define WS_WLO   69206016
#define WS_AOHI  71303168
#define WS_AOLO  88080384

// ================= prep kernels: one-time f32 -> bf16 hi/lo images =================
// K image per (bh): 16 tiles of 64 keys; each tile = 2 d-half blocks of 16KB:
// block byte = key*256 + hl*128 + ((dloc*2) ^ ((key&7)<<4)), dloc = d - dh*64
__global__ __launch_bounds__(256)
void prep_k(const float* __restrict__ gk, char* __restrict__ kimg) {
  const int blk = blockIdx.x;                // bh*16 + it
  const int bh = blk >> 4, it = blk & 15;
  const int bb = bh >> 3, hh = bh & 7;
  const int t = threadIdx.x;
  char* base = kimg + (size_t)bh * 524288 + it * 32768;
  const float* src = gk + ((size_t)bb * N_ + it * 64) * DIM_ + hh * HD_;
  #pragma unroll
  for (int c = 0; c < 8; ++c) {
    const int idx = t + 256 * c;
    const int key = idx >> 5, dq = (idx & 31) * 4;   // d quad 0..124
    f32x4 f = *(const f32x4*)(src + (size_t)key * DIM_ + dq);
    u16x4 h, g;
    #pragma unroll
    for (int j = 0; j < 4; ++j) {
      unsigned short hv = f2bf(f[j]);
      h[j] = hv;
      g[j] = f2bf(f[j] - bf2f(hv));
    }
    const int dh = dq >> 6, dloc = dq & 63;
    const int off = (dloc * 2) ^ ((key & 7) << 4);
    char* dst = base + dh * 16384 + key * 256;
    *(u16x4*)(dst + off) = h;
    *(u16x4*)(dst + 128 + off) = g;
  }
}

// V image per (bh, vtile of 32 keys): 16KB = [hi 8KB | lo 8KB],
// plane byte: (d*64 + key*2) ^ ((d&7)<<4)   (d-major: transposed)
__global__ __launch_bounds__(256)
void prep_v(const float* __restrict__ gv, char* __restrict__ vimg) {
  __shared__ float tile[32][132];
  const int blk = blockIdx.x;                // bh*32 + kt
  const int bh = blk >> 5, kt = blk & 31;
  const int bb = bh >> 3, hh = bh & 7;
  const int t = threadIdx.x;
  const float* src = gv + ((size_t)bb * N_ + kt * 32) * DIM_ + hh * HD_;
  #pragma unroll
  for (int c = 0; c < 4; ++c) {
    const int idx = t + 256 * c;
    const int key = idx >> 5, dq = (idx & 31) * 4;
    *(f32x4*)&tile[key][dq] = *(const f32x4*)(src + (size_t)key * DIM_ + dq);
  }
  __syncthreads();
  char* base = vimg + (size_t)bh * 524288 + kt * 16384;
  #pragma unroll
  for (int c = 0; c < 2; ++c) {
    const int oc = t + 256 * c;              // 0..511
    const int d = oc >> 2, kc = oc & 3;
    u16x8 h, g;
    #pragma unroll
    for (int j = 0; j < 8; ++j) {
      float x = tile[kc * 8 + j][d];
      unsigned short hv = f2bf(x);
      h[j] = hv;
      g[j] = f2bf(x - bf2f(hv));
    }
    const int off = (d * 64 + kc * 16) ^ ((d & 7) << 4);
    *(u16x8*)(base + off) = h;
    *(u16x8*)(base + 8192 + off) = g;
  }
}

// W planes: plain row-major bf16 hi/lo [1024][1024]
__global__ __launch_bounds__(256)
void prep_w(const float* __restrict__ gw, unsigned short* __restrict__ whi,
            unsigned short* __restrict__ wlo) {
  const int idx = blockIdx.x * 256 + threadIdx.x;  // 0..131071
  const int row = idx >> 7, k0 = (idx & 127) * 8;
  const float* s = gw + (size_t)row * DIM_ + k0;
  f32x4 f0 = *(const f32x4*)s;
  f32x4 f1 = *(const f32x4*)(s + 4);
  u16x8 h, g;
  #pragma unroll
  for (int j = 0; j < 8; ++j) {
    float x = j < 4 ? f0[j] : f1[j - 4];
    unsigned short hv = f2bf(x);
    h[j] = hv;
    g[j] = f2bf(x - bf2f(hv));
  }
  *(u16x8*)(whi + (size_t)row * DIM_ + k0) = h;
  *(u16x8*)(wlo + (size_t)row * DIM_ + k0) = g;
}

// ================= attention kernel =================
struct K1Smem {
  unsigned short p[64 * 1024];            // 131072 B: p[row][key] bf16, byte ^ ((row&7)<<4)
  union {
    char kb[2][16384];                    // K half-d tiles (dbuf)
    char vt[2][16384];                    // V tiles (dbuf)
    struct { char pad[16384]; float partial[4][64]; float rinv[64]; } pp;
  } u;
};

__global__ __launch_bounds__(512, 2)
void attn_kernel(const float* __restrict__ gq, const char* __restrict__ kimg,
                 const char* __restrict__ vimg, float* __restrict__ gattn,
                 unsigned short* __restrict__ aohi, unsigned short* __restrict__ aolo) {
  __shared__ K1Smem sm;
  const int bid = blockIdx.x;
  // XCD swizzle: 16 q-tiles of one (b,h) share an XCD
  const int xcd = bid & 7, slot = bid >> 3;
  const int bh = xcd + 8 * (slot >> 4);
  const int qt = slot & 15;
  const int bb = bh >> 3, hh = bh & 7;

  const int tid = threadIdx.x;
  const int wid = tid >> 6, lane = tid & 63;
  const int rg = wid >> 2;                   // 0..1: row half
  const int kg = wid & 3;                    // 0..3: key group (QK) / d group (PV)
  const int l15 = lane & 15, l4 = lane >> 4;

  const char* kimg_bh = kimg + (size_t)bh * 524288;
  const char* vimg_bh = vimg + (size_t)bh * 524288;

  auto issueK = [&](int s) {                 // 16KB tile s (= it*2+dh) -> kb[s&1]
    const char* src = kimg_bh + s * 16384 + wid * 2048 + lane * 16;
    char* dst = sm.u.kb[s & 1] + wid * 2048;
    gl_lds16(src, dst);
    gl_lds16(src + 1024, dst + 1024);
  };
  auto issueV = [&](int kt) {                // 16KB tile kt -> vt[kt&1]
    const char* src = vimg_bh + kt * 16384 + wid * 2048 + lane * 16;
    char* dst = sm.u.vt[kt & 1] + wid * 2048;
    gl_lds16(src, dst);
    gl_lds16(src + 1024, dst + 1024);
  };

  issueK(0);                                 // tile 0 flies during Q conversion

  // ---------------- Q fragments (pre-scaled, hi/lo split) ----------------
  u16x8 qhi[2][4], qlo[2][4];
  #pragma unroll
  for (int rt = 0; rt < 2; ++rt) {
    const int qrow = qt * 64 + rg * 32 + rt * 16 + l15;
    const float* qp = gq + ((size_t)bb * N_ + qrow) * DIM_ + hh * HD_;
    #pragma unroll
    for (int t = 0; t < 4; ++t) {
      const int d0 = t * 32 + l4 * 8;
      f32x4 f0 = *(const f32x4*)(qp + d0);
      f32x4 f1 = *(const f32x4*)(qp + d0 + 4);
      #pragma unroll
      for (int j = 0; j < 8; ++j) {
        float x = (j < 4 ? f0[j] : f1[j - 4]) * SCALE_;
        unsigned short hi = f2bf(x);
        qhi[rt][t][j] = hi;
        qlo[rt][t][j] = f2bf(x - bf2f(hi));
      }
    }
  }

  issueK(1);
  asm volatile("s_waitcnt vmcnt(2)" ::: "memory");  // tile 0 landed (tile 1 in flight)
  SBAR();

  // ---------------- Phase 1: S = K Q^T (swapped: D[key][qrow]) ----------------
  float lsum0 = 0.f, lsum1 = 0.f;
  const int key16 = kg * 16 + l15;
  const int kswz = (key16 & 7) << 4;
  const char* krow0 = sm.u.kb[0] + key16 * 256;
  const char* krow1 = sm.u.kb[1] + key16 * 256;
  char* const prow0 = (char*)sm.p + (rg * 32 + l15) * 2048;
  char* const prow1 = (char*)sm.p + (rg * 32 + 16 + l15) * 2048;
  const int pswz0 = ((rg * 32 + l15) & 7) << 4;
  const int pswz1 = ((rg * 32 + 16 + l15) & 7) << 4;

  f32x4 a0[2], a1[2], a2[2];
  #pragma unroll 2
  for (int s = 0; s < 32; ++s) {
    const int dh = s & 1;
    if (s >= 1 && s < 31) issueK(s + 1);     // into kb[(s+1)&1]: readers done last iter
    else if (s == 31) issueV(0);             // vt[0] aliases kb[0]: dead since s==30
    const char* krow = dh ? krow1 : krow0;   // buffer index == s&1 == dh
    u16x8 khi[2], klo[2];
    #pragma unroll
    for (int tl = 0; tl < 2; ++tl) {
      const int off = (tl * 64 + l4 * 16) ^ kswz;
      khi[tl] = *(const u16x8*)(krow + off);
      klo[tl] = *(const u16x8*)(krow + 128 + off);
    }
    if (dh == 0) {
      #pragma unroll
      for (int rt = 0; rt < 2; ++rt) {
        a0[rt] = f32x4{0.f, 0.f, 0.f, 0.f};
        a1[rt] = f32x4{0.f, 0.f, 0.f, 0.f};
        a2[rt] = f32x4{0.f, 0.f, 0.f, 0.f};
      }
    }
    #pragma unroll
    for (int tl = 0; tl < 2; ++tl) {
      const int t = dh * 2 + tl;
      #pragma unroll
      for (int rt = 0; rt < 2; ++rt) {
        a0[rt] = mfma16(khi[tl], qhi[rt][t], a0[rt]);
        a1[rt] = mfma16(klo[tl], qhi[rt][t], a1[rt]);
        a2[rt] = mfma16(khi[tl], qlo[rt][t], a2[rt]);
      }
    }
    if (dh == 1) {
      const int keyb = ((s >> 1) * 64 + kg * 16 + l4 * 4) * 2;
      #pragma unroll
      for (int rt = 0; rt < 2; ++rt) {
        u16x4 pk;
        float ls = 0.f;
        #pragma unroll
        for (int r = 0; r < 4; ++r) {
          float sv = (a0[rt][r] + a1[rt][r]) + a2[rt][r];
          sv = fminf(sv, 60.0f);
          float p = __expf(sv);
          ls += p;
          pk[r] = f2bf(p);
        }
        if (rt == 0) { lsum0 += ls; *(u16x4*)(prow0 + (keyb ^ pswz0)) = pk; }
        else         { lsum1 += ls; *(u16x4*)(prow1 + (keyb ^ pswz1)) = pk; }
      }
    }
    if (s < 31) { asm volatile("s_waitcnt vmcnt(0)" ::: "memory"); }
    else        { asm volatile("s_waitcnt vmcnt(2)" ::: "memory"); }  // keep V0 in flight
    SBAR();
  }

  // ---------------- rowsums -> partial -> rinv table ----------------
  {
    float s0 = lsum0; s0 += __shfl_xor(s0, 16); s0 += __shfl_xor(s0, 32);
    float s1 = lsum1; s1 += __shfl_xor(s1, 16); s1 += __shfl_xor(s1, 32);
    if (lane < 16) {
      sm.u.pp.partial[kg][rg * 32 + lane] = s0;
      sm.u.pp.partial[kg][rg * 32 + 16 + lane] = s1;
    }
  }
  LGKM0();
  SBAR();
  if (tid < 64) {
    float t4 = sm.u.pp.partial[0][tid] + sm.u.pp.partial[1][tid] +
               sm.u.pp.partial[2][tid] + sm.u.pp.partial[3][tid];
    sm.u.pp.rinv[tid] = 1.0f / t4;
  }
  LGKM0();
  SBAR();
  float rvf[2][4];
  #pragma unroll
  for (int rt = 0; rt < 2; ++rt)
    #pragma unroll
    for (int r = 0; r < 4; ++r)
      rvf[rt][r] = sm.u.pp.rinv[rg * 32 + rt * 16 + l4 * 4 + r];
  const bool writer = (kg < 2);
  float rvw = 0.f;
  if (writer) rvw = sm.u.pp.rinv[rg * 32 + kg * 16 + l15];
  LGKM0();                                   // all rinv/partial reads complete
  asm volatile("s_waitcnt vmcnt(0)" ::: "memory");  // V0 landed
  SBAR();

  // ---------------- Phase 2: PV (dbuf vt) + fused attn write from pa regs ----------------
  f32x4 oacc[2][2];
  #pragma unroll
  for (int rt = 0; rt < 2; ++rt)
    #pragma unroll
    for (int ct = 0; ct < 2; ++ct) oacc[rt][ct] = f32x4{0.f, 0.f, 0.f, 0.f};

  float* arow = nullptr;
  if (writer)
    arow = gattn + ((size_t)bh * N_ + qt * 64 + rg * 32 + kg * 16 + l15) * N_ + l4 * 8;

  #pragma unroll 2
  for (int kt = 0; kt < 32; ++kt) {
    if (kt < 31) issueV(kt + 1);
    const char* vbase = sm.u.vt[kt & 1];
    u16x8 vh[2], vl[2];
    #pragma unroll
    for (int ct = 0; ct < 2; ++ct) {
      const int d = kg * 32 + ct * 16 + l15;
      const int off = (d * 64 + l4 * 16) ^ ((d & 7) << 4);
      vh[ct] = *(const u16x8*)(vbase + off);
      vl[ct] = *(const u16x8*)(vbase + 8192 + off);
    }
    const int pb = kt * 64 + l4 * 16;
    u16x8 pa0 = *(const u16x8*)(prow0 + (pb ^ pswz0));
    u16x8 pa1 = *(const u16x8*)(prow1 + (pb ^ pswz1));
    #pragma unroll
    for (int ct = 0; ct < 2; ++ct) {
      oacc[0][ct] = mfma16(pa0, vh[ct], oacc[0][ct]);
      oacc[0][ct] = mfma16(pa0, vl[ct], oacc[0][ct]);
      oacc[1][ct] = mfma16(pa1, vh[ct], oacc[1][ct]);
      oacc[1][ct] = mfma16(pa1, vl[ct], oacc[1][ct]);
    }
    if (writer) {
      u16x8 pw = (kg == 0) ? pa0 : pa1;
      f32x4 o0, o1;
      o0[0] = bf2f(pw[0]) * rvw; o0[1] = bf2f(pw[1]) * rvw;
      o0[2] = bf2f(pw[2]) * rvw; o0[3] = bf2f(pw[3]) * rvw;
      o1[0] = bf2f(pw[4]) * rvw; o1[1] = bf2f(pw[5]) * rvw;
      o1[2] = bf2f(pw[6]) * rvw; o1[3] = bf2f(pw[7]) * rvw;
      __builtin_nontemporal_store(o0, (f32x4*)(arow + kt * 32));
      __builtin_nontemporal_store(o1, (f32x4*)(arow + kt * 32 + 4));
    }
    if (kt < 31) {
      if (writer) asm volatile("s_waitcnt vmcnt(2)" ::: "memory");  // leave 2 stores in flight
      else        asm volatile("s_waitcnt vmcnt(0)" ::: "memory");
    }
    SBAR();
  }

  // ---------------- epilogue: ao = (PV)*rinv as bf16 hi/lo planes ----------------
  #pragma unroll
  for (int rt = 0; rt < 2; ++rt)
    #pragma unroll
    for (int ct = 0; ct < 2; ++ct) {
      const int col = hh * HD_ + kg * 32 + ct * 16 + l15;
      const int row0 = bb * N_ + qt * 64 + rg * 32 + rt * 16 + l4 * 4;
      #pragma unroll
      for (int r = 0; r < 4; ++r) {
        float val = oacc[rt][ct][r] * rvf[rt][r];
        unsigned short hv = f2bf(val);
        unsigned short lv = f2bf(val - bf2f(hv));
        const size_t off = (size_t)(row0 + r) * DIM_ + col;
        __builtin_nontemporal_store(hv, aohi + off);
        __builtin_nontemporal_store(lv, aolo + off);
      }
    }
}

// ================= K2: out = ao @ W^T + b (bf16x3, pre-split operands) =================
struct K2Smem {
  unsigned short A[128 * 2 * 32];   // byte = row*128 + ((hl*64 + k*2) ^ ((row&7)<<4))
  unsigned short Bm[128 * 2 * 32];
};

__global__ __launch_bounds__(512)
void proj_kernel(const unsigned short* __restrict__ aohi, const unsigned short* __restrict__ aolo,
                 const unsigned short* __restrict__ whi, const unsigned short* __restrict__ wlo,
                 const float* __restrict__ gbias, float* __restrict__ gout) {
  __shared__ K2Smem sm;
  const int bid = blockIdx.x;
  const int mt = bid >> 3, nt = bid & 7;
  const int m0 = mt * 128, n0 = nt * 128;
  const int tid = threadIdx.x;
  const int wid = tid >> 6, lane = tid & 63;
  const int wr = wid >> 1, wc = wid & 1;
  const int l15 = lane & 15, l4 = lane >> 4;

  f32x4 acc[2][4];
  #pragma unroll
  for (int i = 0; i < 2; ++i)
    #pragma unroll
    for (int j = 0; j < 4; ++j) acc[i][j] = f32x4{0.f, 0.f, 0.f, 0.f};

  #pragma unroll 1
  for (int step = 0; step < 32; ++step) {
    const int k0 = step * 32;
    if (step) __syncthreads();
    #pragma unroll
    for (int c0 = 0; c0 < 4; ++c0) {
      const int c = tid + 512 * c0;          // 0..2047
      const int mat = c >> 10;               // 0:A 1:B
      const int cc = c & 1023;
      const int row = cc >> 3, hl = (cc >> 2) & 1, ch = cc & 3;
      const unsigned short* plane = mat == 0 ? (hl ? aolo : aohi) : (hl ? wlo : whi);
      const size_t grow = (size_t)((mat == 0 ? m0 : n0) + row);
      u16x8 vdat = *(const u16x8*)(plane + grow * DIM_ + k0 + ch * 8);
      char* lbase = (mat == 0 ? (char*)sm.A : (char*)sm.Bm) + row * 128;
      *(u16x8*)(lbase + ((hl * 64 + ch * 16) ^ ((row & 7) << 4))) = vdat;
    }
    __syncthreads();

    u16x8 ah[2], al[2], bh[4], bl[4];
    #pragma unroll
    for (int t = 0; t < 2; ++t) {
      const int row = wr * 32 + t * 16 + l15;
      const char* rp = (char*)sm.A + row * 128;
      const int swz = (row & 7) << 4;
      ah[t] = *(const u16x8*)(rp + ((l4 * 16) ^ swz));
      al[t] = *(const u16x8*)(rp + ((64 + l4 * 16) ^ swz));
    }
    #pragma unroll
    for (int t = 0; t < 4; ++t) {
      const int col = wc * 64 + t * 16 + l15;
      const char* rp = (char*)sm.Bm + col * 128;
      const int swz = (col & 7) << 4;
      bh[t] = *(const u16x8*)(rp + ((l4 * 16) ^ swz));
      bl[t] = *(const u16x8*)(rp + ((64 + l4 * 16) ^ swz));
    }
    #pragma unroll
    for (int i = 0; i < 2; ++i)
      #pragma unroll
      for (int j = 0; j < 4; ++j)
        acc[i][j] = mfma16(ah[i], bh[j], acc[i][j]);
    #pragma unroll
    for (int i = 0; i < 2; ++i)
      #pragma unroll
      for (int j = 0; j < 4; ++j)
        acc[i][j] = mfma16(ah[i], bl[j], acc[i][j]);
    #pragma unroll
    for (int i = 0; i < 2; ++i)
      #pragma unroll
      for (int j = 0; j < 4; ++j)
        acc[i][j] = mfma16(al[i], bh[j], acc[i][j]);
  }

  #pragma unroll
  for (int i = 0; i < 2; ++i) {
    #pragma unroll
    for (int j = 0; j < 4; ++j) {
      const int col = n0 + wc * 64 + j * 16 + l15;
      const float bv = gbias[col];
      float* dst = gout + (size_t)(m0 + wr * 32 + i * 16 + l4 * 4) * DIM_ + col;
      #pragma unroll
      for (int r = 0; r < 4; ++r)
        dst[(size_t)r * DIM_] = acc[i][j][r] + bv;
    }
  }
}

extern "C" void kernel_launch(void* const* d_in, const int* in_sizes, int n_in,
                              void* d_out, int out_size, void* d_ws, size_t ws_size,
                              hipStream_t stream) {
  const float* q    = (const float*)d_in[0];
  const float* k    = (const float*)d_in[1];
  const float* v    = (const float*)d_in[2];
  const float* W    = (const float*)d_in[3];
  const float* bias = (const float*)d_in[4];
  float* out  = (float*)d_out;
  float* attn = out + (size_t)B_ * N_ * DIM_;      // outputs: [out | attn]

  char* ws = (char*)d_ws;                          // needs 100 MB
  char* kimg = ws + WS_KIMG;
  char* vimg = ws + WS_VIMG;
  unsigned short* whi  = (unsigned short*)(ws + WS_WHI);
  unsigned short* wlo  = (unsigned short*)(ws + WS_WLO);
  unsigned short* aohi = (unsigned short*)(ws + WS_AOHI);
  unsigned short* aolo = (unsigned short*)(ws + WS_AOLO);

  prep_k<<<64 * 16, 256, 0, stream>>>(k, kimg);
  prep_v<<<64 * 32, 256, 0, stream>>>(v, vimg);
  prep_w<<<512, 256, 0, stream>>>(W, whi, wlo);
  attn_kernel<<<B_ * H_ * (N_ / 64), 512, 0, stream>>>(q, kimg, vimg, attn, aohi, aolo);
  proj_kernel<<<(B_ * N_ / 128) * (DIM_ / 128), 512, 0, stream>>>(aohi, aolo, whi, wlo, bias, out);
}